// Round 2
// 368.615 us; speedup vs baseline: 1.2898x; 1.2898x over previous
//
#include <hip/hip_runtime.h>
#include <math.h>

#define BB 8
#define TT 100
#define HH 1024
#define LL 512
#define VV 32000
#define NROWS (BB*TT)   // 800
#define MPAD 896        // 7 tiles of 128
#define NMT 7           // m tiles
#define NNT 250         // n tiles
#define NWG (NMT*NNT)   // 1750

typedef __bf16 bf16x8 __attribute__((ext_vector_type(8)));
typedef __bf16 bf16x4 __attribute__((ext_vector_type(4)));
typedef float f32x4 __attribute__((ext_vector_type(4)));

__device__ __forceinline__ void gload16(const void* g, void* l) {
  __builtin_amdgcn_global_load_lds(
      (const __attribute__((address_space(1))) unsigned int*)g,
      (__attribute__((address_space(3))) unsigned int*)l, 16, 0, 0);
}

// ---------- kernel 1: x fp32 -> bf16, zero-padded to 896 rows ----------
__global__ __launch_bounds__(256) void k_cvt_x(const float* __restrict__ x,
                                               __bf16* __restrict__ xb) {
  int idx = blockIdx.x * 256 + threadIdx.x;   // one float4 per thread
  int row = (idx * 4) >> 10;
  bf16x4 v;
  if (row < NROWS) {
    float4 f = ((const float4*)x)[idx];
    v[0] = (__bf16)f.x; v[1] = (__bf16)f.y; v[2] = (__bf16)f.z; v[3] = (__bf16)f.w;
  } else {
    v[0] = v[1] = v[2] = v[3] = (__bf16)0.f;
  }
  ((bf16x4*)xb)[idx] = v;
}

// ---------- kernel 2: W [1024][32000] fp32 -> blocked Wt [kt][n][32] bf16 ----
// Layout: Wtb[((kt*VV)+n)*32 + kin], kt = k/32.
// Write phase: lane t writes byte (g*64 + t>>2)*64 + (t&3)*16 = g*4096 + t*16
// -> perfectly coalesced 1 KB per wave. LDS read is 2-way bank alias (free).
__global__ __launch_bounds__(256) void k_cvt_wT(const float* __restrict__ W,
                                                __bf16* __restrict__ Wtb) {
  __shared__ float T[32][257];
  int n0 = blockIdx.x * 256;   // 125 blocks
  int kt = blockIdx.y;         // 32 blocks
  int tid = threadIdx.x;
#pragma unroll
  for (int i = 0; i < 32; ++i)
    T[i][tid] = W[(size_t)(kt * 32 + i) * VV + n0 + tid];
  __syncthreads();
  int cq = tid & 3;    // k-chunk (8 k each)
  int cl = tid >> 2;   // 0..63
  __bf16* base = Wtb + ((size_t)kt * VV + n0) * 32;
#pragma unroll
  for (int g = 0; g < 4; ++g) {
    int col = g * 64 + cl;
    bf16x8 v;
#pragma unroll
    for (int j = 0; j < 8; ++j) v[j] = (__bf16)T[cq * 8 + j][col];
    *(bf16x8*)(base + (size_t)col * 32 + cq * 8) = v;
  }
}

// ---------- kernel 3: p_gen + copy distribution (+ rsum zero-init) ----------
__global__ __launch_bounds__(256) void k_pgen_copy(
    const float* __restrict__ x, const float* __restrict__ attn,
    const float* __restrict__ w_gen, const float* __restrict__ b_gen,
    float* __restrict__ p_gen, float* __restrict__ copy_dist,
    float* __restrict__ rsum) {
  int r = blockIdx.x;
  int tid = threadIdx.x;
  __shared__ float red[4];
  if (tid == 0) rsum[r] = 0.f;   // replaces hipMemsetAsync dispatch

  float d = 0.f;
  for (int h = tid; h < HH; h += 256) d += x[(size_t)r * HH + h] * w_gen[h];
#pragma unroll
  for (int o = 32; o > 0; o >>= 1) d += __shfl_down(d, o, 64);
  if ((tid & 63) == 0) red[tid >> 6] = d;
  __syncthreads();
  float dot = red[0] + red[1] + red[2] + red[3];
  float p = 1.f / (1.f + __expf(-(dot + b_gen[0])));
  if (tid == 0) p_gen[r] = p;

  float a0 = attn[(size_t)r * LL + tid];
  float a1 = attn[(size_t)r * LL + 256 + tid];
  float m = fmaxf(a0, a1);
#pragma unroll
  for (int o = 32; o > 0; o >>= 1) m = fmaxf(m, __shfl_down(m, o, 64));
  __syncthreads();
  if ((tid & 63) == 0) red[tid >> 6] = m;
  __syncthreads();
  float M = fmaxf(fmaxf(red[0], red[1]), fmaxf(red[2], red[3]));
  float e0 = __expf(a0 - M), e1 = __expf(a1 - M);
  float s = e0 + e1;
#pragma unroll
  for (int o = 32; o > 0; o >>= 1) s += __shfl_down(s, o, 64);
  __syncthreads();
  if ((tid & 63) == 0) red[tid >> 6] = s;
  __syncthreads();
  float S = red[0] + red[1] + red[2] + red[3];
  float scale = (1.f - p) / S;
  copy_dist[(size_t)r * LL + tid] = e0 * scale;
  copy_dist[(size_t)r * LL + 256 + tid] = e1 * scale;
}

// ---------- kernel 4: bf16 MFMA GEMM, double-buffered LDS ----------
// PROVEN round-0 sync structure: __syncthreads() drain at loop top, stage k+1
// into buf[1-cur], compute buf[cur]. Only two changes vs the verified kernel:
//  (a) bijective XCD-chunked remap, m-fastest: the 7 blocks sharing a B-panel
//      are consecutive wgs on ONE XCD -> B fetched ~once from HBM.
//  (b) B reads use the blocked Wt [kt][n][32] layout (1 KB contiguous/wave).
__global__ __launch_bounds__(256) void k_gemm_mfma(
    const __bf16* __restrict__ Xb, const __bf16* __restrict__ Wtb,
    const float* __restrict__ bias, float* __restrict__ out,
    float* __restrict__ rsum) {
  __shared__ __align__(16) __bf16 As[2][128 * 32];  // [m][k] k-contiguous
  __shared__ __align__(16) __bf16 Bs[2][128 * 32];  // [n][k] k-contiguous
  int tid = threadIdx.x;
  int lane = tid & 63, wave = tid >> 6;
  int wr = wave >> 1, wc = wave & 1;
  int l15 = lane & 15, quad = lane >> 4;

  // bijective XCD remap (m204 form): lid%8 = XCD, chunk size q/q+1
  int lid = blockIdx.x;
  int xcd = lid & 7, sub = lid >> 3;
  const int q = NWG >> 3, rr = NWG & 7;   // 218, 6
  int wg = (xcd < rr) ? (xcd * (q + 1) + sub)
                      : (rr * (q + 1) + (xcd - rr) * q + sub);
  int m0 = (wg % NMT) * 128;
  int n0 = (wg / NMT) * 128;

  f32x4 acc[4][4];
#pragma unroll
  for (int mi = 0; mi < 4; ++mi)
#pragma unroll
    for (int ni = 0; ni < 4; ++ni) acc[mi][ni] = (f32x4){0.f, 0.f, 0.f, 0.f};

  int r0 = wave * 32;
  const __bf16* aptr0 = Xb + (size_t)(m0 + r0 + (lane >> 2)) * HH + (lane & 3) * 8;
  const __bf16* aptr1 = aptr0 + (size_t)16 * HH;
  const size_t bstep = (size_t)VV * 32;
  // blocked B: [kt][n][32]; per-lane 16 B, 4 lanes/row -> 1 KB contiguous/wave
  const __bf16* bptr0 = Wtb + (size_t)(n0 + r0 + (lane >> 2)) * 32 + (lane & 3) * 8;
  const __bf16* bptr1 = bptr0 + (size_t)16 * 32;

  // wave-uniform LDS bases, per buffer
  __bf16* lA0[2] = {&As[0][r0 * 32], &As[1][r0 * 32]};
  __bf16* lA1[2] = {&As[0][(r0 + 16) * 32], &As[1][(r0 + 16) * 32]};
  __bf16* lB0[2] = {&Bs[0][r0 * 32], &Bs[1][r0 * 32]};
  __bf16* lB1[2] = {&Bs[0][(r0 + 16) * 32], &Bs[1][(r0 + 16) * 32]};

  // prologue: stage k-slice 0 into buffer 0
  gload16(aptr0, lA0[0]);
  gload16(aptr1, lA1[0]);
  gload16(bptr0, lB0[0]);
  gload16(bptr1, lB1[0]);

  for (int it = 0; it < 32; ++it) {
    int cur = it & 1;
    __syncthreads();  // vmcnt(0) drain: buf[cur] fully staged (and prev reads done)
    if (it + 1 < 32) {
      int ko = (it + 1) * 32;
      size_t bo = (size_t)(it + 1) * bstep;
      int nxt = cur ^ 1;
      gload16(aptr0 + ko, lA0[nxt]);
      gload16(aptr1 + ko, lA1[nxt]);
      gload16(bptr0 + bo, lB0[nxt]);
      gload16(bptr1 + bo, lB1[nxt]);
    }
    const __bf16* Ab = As[cur];
    const __bf16* Bb = Bs[cur];
    bf16x8 af[4], bfg[4];
#pragma unroll
    for (int mi = 0; mi < 4; ++mi)
      af[mi] = *(const bf16x8*)&Ab[(wr * 64 + mi * 16 + l15) * 32 + quad * 8];
#pragma unroll
    for (int ni = 0; ni < 4; ++ni)
      bfg[ni] = *(const bf16x8*)&Bb[(wc * 64 + ni * 16 + l15) * 32 + quad * 8];
#pragma unroll
    for (int mi = 0; mi < 4; ++mi)
#pragma unroll
      for (int ni = 0; ni < 4; ++ni)
        acc[mi][ni] = __builtin_amdgcn_mfma_f32_16x16x32_bf16(af[mi], bfg[ni], acc[mi][ni], 0, 0, 0);
  }

  float bv4[4];
#pragma unroll
  for (int ni = 0; ni < 4; ++ni) bv4[ni] = bias[n0 + wc * 64 + ni * 16 + l15];

#pragma unroll
  for (int mi = 0; mi < 4; ++mi) {
#pragma unroll
    for (int rg = 0; rg < 4; ++rg) {
      int row = m0 + wr * 64 + mi * 16 + quad * 4 + rg;
      bool valid = row < NROWS;
      float esum = 0.f;
#pragma unroll
      for (int ni = 0; ni < 4; ++ni) {
        int col = n0 + wc * 64 + ni * 16 + l15;
        float v = acc[mi][ni][rg] + bv4[ni];
        if (valid) out[(size_t)row * VV + col] = v;
        esum += __expf(v);
      }
#pragma unroll
      for (int o = 8; o > 0; o >>= 1) esum += __shfl_down(esum, o, 16);
      if (l15 == 0 && valid) atomicAdd(&rsum[row], esum);
    }
  }
}

// ---------- kernel 5: affine log-shift (streaming, fully parallel) ----------
__global__ __launch_bounds__(256) void k_affine(
    float* __restrict__ out, const float* __restrict__ p_gen,
    const float* __restrict__ rsum) {
  int r = blockIdx.y;
  int c = (blockIdx.x * 256 + threadIdx.x) * 4;
  if (c >= VV) return;
  float logc = __logf(p_gen[r] / rsum[r]);
  float4 v = *(float4*)&out[(size_t)r * VV + c];
  v.x += logc; v.y += logc; v.z += logc; v.w += logc;
  *(float4*)&out[(size_t)r * VV + c] = v;
}

// ---------- kernel 6: scatter fix-up at copied columns only ----------
__global__ __launch_bounds__(256) void k_scatter_fix(
    float* __restrict__ out, const int* __restrict__ enc,
    const float* __restrict__ copy) {
  __shared__ int hkey[1024];
  __shared__ float hval[1024];
  int r = blockIdx.x, tid = threadIdx.x;
  float* row = out + (size_t)r * VV;
  for (int i = tid; i < 1024; i += 256) { hkey[i] = -1; hval[i] = 0.f; }
  __syncthreads();
  int b = r / TT;
  for (int j = tid; j < LL; j += 256) {
    int v = enc[(size_t)b * LL + j];
    float cv = copy[(size_t)r * LL + j];
    unsigned h = ((unsigned)v * 2654435761u) & 1023u;
    while (true) {
      int prev = atomicCAS(&hkey[h], -1, v);
      if (prev == -1 || prev == v) { atomicAdd(&hval[h], cv); break; }
      h = (h + 1) & 1023u;
    }
  }
  __syncthreads();
  for (int h = tid; h < 1024; h += 256) {
    int col = hkey[h];
    if (col >= 0) {
      float stored = row[col];  // = log(p_gen*softmax) at this col
      row[col] = __logf(__expf(stored) + hval[h]);
    }
  }
}

extern "C" void kernel_launch(void* const* d_in, const int* in_sizes, int n_in,
                              void* d_out, int out_size, void* d_ws, size_t ws_size,
                              hipStream_t stream) {
  const float* x    = (const float*)d_in[0];
  const float* attn = (const float*)d_in[1];
  const int*   enc  = (const int*)d_in[2];
  const float* Wv   = (const float*)d_in[3];
  const float* bv   = (const float*)d_in[4];
  const float* wgen = (const float*)d_in[5];
  const float* bg   = (const float*)d_in[6];
  float* out = (float*)d_out;
  float* ws = (float*)d_ws;

  float* p_gen = ws;                                   // 1024 floats
  float* rsum  = ws + 1024;                            // 1024 floats
  float* copy  = ws + 2048;                            // 800*512 floats
  __bf16* xb = (__bf16*)(ws + 2048 + NROWS * LL);      // 896*1024 bf16
  __bf16* Wt = (__bf16*)((char*)xb + (size_t)MPAD * HH * 2);  // 32000*1024 bf16 (blocked)

  k_cvt_x<<<MPAD * HH / 4 / 256, 256, 0, stream>>>(x, xb);
  dim3 gw(VV / 256, HH / 32);   // (125, 32)
  k_cvt_wT<<<gw, 256, 0, stream>>>(Wv, Wt);
  k_pgen_copy<<<NROWS, 256, 0, stream>>>(x, attn, wgen, bg, p_gen, copy, rsum);
  k_gemm_mfma<<<NWG, 256, 0, stream>>>(xb, Wt, bv, out, rsum);
  dim3 ga((VV + 1023) / 1024, NROWS);
  k_affine<<<ga, 256, 0, stream>>>(out, p_gen, rsum);
  k_scatter_fix<<<NROWS, 256, 0, stream>>>(out, enc, copy);
}